// Round 10
// baseline (287.778 us; speedup 1.0000x reference)
//
#include <hip/hip_runtime.h>

#define BS   32
#define SLEN 4096
#define EM   256
#define NROWS (BS * SLEN)  // 131072

typedef __attribute__((ext_vector_type(8))) short bf16x8;
typedef __attribute__((ext_vector_type(4))) float f32x4;

// ---------------- ws layout (floats) ----------------
#define WS_WKB   0         // 32768  : wk bf16, fragment-major [kq][e][8]
#define WS_EN    32768     // 131072 : raw energy
#define WS_CONST 163840    // 16     : scalar energy_q + be
#define WS_W     163856    // 131072 : softmax weights
#define WS_PART  294928    // 524288 : wsum partials (32b x 64ch) x 256

__device__ inline short f2bf(float x) {
  union { float f; unsigned u; } v; v.f = x;
  unsigned r = v.u + 0x7fffu + ((v.u >> 16) & 1u);  // RNE
  return (short)(r >> 16);
}

// packed f32x2 -> bf16x2 (RNE), gfx950 v_cvt_pk_bf16_f32 (no builtin; T12 recipe)
__device__ inline unsigned cvtpk(float lo, float hi) {
  unsigned r;
  asm("v_cvt_pk_bf16_f32 %0, %1, %2" : "=v"(r) : "v"(lo), "v"(hi));
  return r;
}
__device__ inline bf16x8 cvt8(float4 a, float4 b) {
  union { bf16x8 v; unsigned u[4]; } r;
  r.u[0] = cvtpk(a.x, a.y);
  r.u[1] = cvtpk(a.z, a.w);
  r.u[2] = cvtpk(b.x, b.y);
  r.u[3] = cvtpk(b.z, b.w);
  return r.v;
}

#define GLOAD_LDS16(g, l)                                                  \
  __builtin_amdgcn_global_load_lds(                                        \
      (const __attribute__((address_space(1))) unsigned int*)(g),          \
      (__attribute__((address_space(3))) unsigned int*)(l), 16, 0, 0)

// ---- K0: wk fp32 [e][k] -> bf16 fragment-major: 16B chunk index kq*256+e ----
__global__ __launch_bounds__(256) void k0_cvt(const float* __restrict__ wk,
                                              unsigned short* __restrict__ wkb2) {
  int gid = blockIdx.x * 256 + threadIdx.x;  // 8192
  int e = gid >> 5, kq = gid & 31;
  const float* src = wk + (size_t)e * EM + kq * 8;
  float4 v0 = *(const float4*)src;
  float4 v1 = *(const float4*)(src + 4);
  bf16x8 pk;
  pk[0] = f2bf(v0.x); pk[1] = f2bf(v0.y); pk[2] = f2bf(v0.z); pk[3] = f2bf(v0.w);
  pk[4] = f2bf(v1.x); pk[5] = f2bf(v1.y); pk[6] = f2bf(v1.z); pk[7] = f2bf(v1.w);
  *(bf16x8*)(wkb2 + ((size_t)kq * 256 + e) * 8) = pk;
}

// ---- K0b: scalar query path ----
__global__ __launch_bounds__(256) void k0b_qscalar(const float* __restrict__ w_query,
                                                   const float* __restrict__ wq,
                                                   const float* __restrict__ bq,
                                                   const float* __restrict__ we,
                                                   const float* __restrict__ be,
                                                   float* __restrict__ outc) {
  int t = threadIdx.x;  // t = e
  const float* row = wq + (size_t)t * EM;
  float4 a4 = make_float4(0.f, 0.f, 0.f, 0.f);
#pragma unroll 8
  for (int j = 0; j < 64; ++j) {
    float4 r = *(const float4*)(row + j * 4);
    float4 q = *(const float4*)(w_query + j * 4);
    a4.x = fmaf(r.x, q.x, a4.x);
    a4.y = fmaf(r.y, q.y, a4.y);
    a4.z = fmaf(r.z, q.z, a4.z);
    a4.w = fmaf(r.w, q.w, a4.w);
  }
  float a = (a4.x + a4.y) + (a4.z + a4.w) + bq[t];
  float kv = fmaxf(a, 0.f);
  float z = __expf(kv + kv);
  float v = we[t] * (1.f - __fdividef(2.f, z + 1.f));
#pragma unroll
  for (int off = 32; off >= 1; off >>= 1) v += __shfl_xor(v, off, 64);
  __shared__ float red[4];
  if ((t & 63) == 0) red[t >> 6] = v;
  __syncthreads();
  if (t == 0) outc[0] = red[0] + red[1] + red[2] + red[3] + be[0];
}

// ---- K1 (MFMA, B-resident-in-LDS, ONE barrier total) ----
// 512 blocks x 512 thr. __launch_bounds__(512, 2): 2 waves/SIMD min ->
// 256-VGPR budget (R8 ran at 128 VGPR and spilled 18MB/dispatch to scratch).
// bkv dies after C-init; wev loaded after the MFMA loop (fewer live regs).
// Stage full wkb (128KB bf16, fragment-major) into LDS once, one barrier,
// then each wave independently streams 32 rows x 256 cols, 8 k-steps:
// prefetch next A (4 float4), cvt_pk A -> 2 frags, 16 ds_read_b128 B frags,
// 32 MFMA. No further barriers.
__global__ __launch_bounds__(512, 2) void k1_energy(const float* __restrict__ X,
                                                    const unsigned short* __restrict__ wkb2,
                                                    const float* __restrict__ bk,
                                                    const float* __restrict__ we,
                                                    float* __restrict__ energy) {
  __shared__ char Bs[131072];
  const int tid = threadIdx.x;
  const int l = tid & 63;
  const int w = tid >> 6;       // wave 0..7
  const int lr = l & 15, lk = l >> 4;
  const int row0 = blockIdx.x * 256 + w * 32;

  // ---- stage all of B: wave w copies segments w*16..w*16+15 (1KB each) ----
#pragma unroll
  for (int q = 0; q < 16; ++q) {
    int seg = w * 16 + q;
    GLOAD_LDS16((const char*)wkb2 + seg * 1024 + l * 16, Bs + seg * 1024);
  }

  f32x4 acc[2][16];
#pragma unroll
  for (int n = 0; n < 16; ++n) {
    float b = bk[n * 16 + lr];  // dies after init
    acc[0][n] = (f32x4){b, b, b, b};
    acc[1][n] = acc[0][n];
  }

  // first A tile in flight before the barrier (independent of LDS)
  const float* xbase = X + (size_t)(row0 + lr) * EM + lk * 8;
  float4 c00 = *(const float4*)(xbase);
  float4 c01 = *(const float4*)(xbase + 4);
  float4 c10 = *(const float4*)(xbase + 16 * EM);
  float4 c11 = *(const float4*)(xbase + 16 * EM + 4);

  __syncthreads();  // only barrier: B resident from here on

#pragma unroll
  for (int s = 0; s < 8; ++s) {
    float4 n00, n01, n10, n11;
    if (s < 7) {
      const float* nx = xbase + (s + 1) * 32;
      n00 = *(const float4*)(nx);
      n01 = *(const float4*)(nx + 4);
      n10 = *(const float4*)(nx + 16 * EM);
      n11 = *(const float4*)(nx + 16 * EM + 4);
    }
    bf16x8 a0 = cvt8(c00, c01);
    bf16x8 a1 = cvt8(c10, c11);
    const char* bp = Bs + s * 16384 + lk * 4096 + lr * 16;
#pragma unroll
    for (int n = 0; n < 16; ++n) {
      bf16x8 bfr = *(const bf16x8*)(bp + n * 256);
      acc[0][n] = __builtin_amdgcn_mfma_f32_16x16x32_bf16(a0, bfr, acc[0][n], 0, 0, 0);
      acc[1][n] = __builtin_amdgcn_mfma_f32_16x16x32_bf16(a1, bfr, acc[1][n], 0, 0, 0);
    }
    c00 = n00; c01 = n01; c10 = n10; c11 = n11;
  }

  // ---- epilogue: p = sumw - 2*sum(we*r), r = 1/(e^2x+1); reduce over cols ----
  float sumw = 0.f, w2[16];
#pragma unroll
  for (int n = 0; n < 16; ++n) {
    float wv = we[EM + n * 16 + lr];  // loaded fresh (L2-hot), not held in loop
    sumw += wv;
    w2[n] = -2.f * wv;
  }
#pragma unroll
  for (int i = 0; i < 2; ++i) {
#pragma unroll
    for (int r = 0; r < 4; ++r) {
      float p = sumw;
#pragma unroll
      for (int n = 0; n < 16; ++n) {
        float kv = fmaxf(acc[i][n][r], 0.f);
        float z = __expf(kv + kv);
        p = fmaf(w2[n], __fdividef(1.f, z + 1.f), p);
      }
#pragma unroll
      for (int off = 1; off <= 8; off <<= 1) p += __shfl_xor(p, off, 16);
      if (lr == 0) energy[row0 + i * 16 + lk * 4 + r] = p;
    }
  }
}

// ---- K2: per-batch masked softmax over SLEN (byte-vs-int32 mask probe) ----
__global__ __launch_bounds__(256) void k2_softmax(const float* __restrict__ energy,
                                                  const unsigned char* __restrict__ mask,
                                                  const float* __restrict__ cptr,
                                                  float* __restrict__ wout) {
  const int b = blockIdx.x;
  const int t = threadIdx.x;
  const float C = cptr[0];
  const bool mask_is_byte = (mask[1] | mask[2] | mask[3]) != 0;
  const int* mask32 = (const int*)mask;
  const float* eb = energy + (size_t)b * SLEN;
  float v[16];
  float m = -3.4e38f;
#pragma unroll
  for (int i = 0; i < 16; ++i) {
    int s = t + i * 256;
    int mv = mask_is_byte ? (int)mask[(size_t)b * SLEN + s]
                          : mask32[(size_t)b * SLEN + s];
    float x = mv ? (eb[s] + C) : 1.4012984643248171e-45f;
    v[i] = x;
    m = fmaxf(m, x);
  }
  __shared__ float red[8];
#pragma unroll
  for (int off = 32; off >= 1; off >>= 1) m = fmaxf(m, __shfl_xor(m, off, 64));
  if ((t & 63) == 0) red[t >> 6] = m;
  __syncthreads();
  m = fmaxf(fmaxf(red[0], red[1]), fmaxf(red[2], red[3]));
  float s_ = 0.f;
#pragma unroll
  for (int i = 0; i < 16; ++i) {
    v[i] = __expf(v[i] - m);
    s_ += v[i];
  }
#pragma unroll
  for (int off = 32; off >= 1; off >>= 1) s_ += __shfl_xor(s_, off, 64);
  if ((t & 63) == 0) red[4 + (t >> 6)] = s_;
  __syncthreads();
  float inv = 1.f / (red[4] + red[5] + red[6] + red[7]);
  float* wb = wout + (size_t)b * SLEN;
#pragma unroll
  for (int i = 0; i < 16; ++i) wb[t + i * 256] = v[i] * inv;
}

// ---- K3: partial weighted sums. 2048 blocks = 32b x 64ch(64 s each) ----
__global__ __launch_bounds__(256) void k3_wsum(const float* __restrict__ X,
                                               const float* __restrict__ w,
                                               float* __restrict__ part) {
  __shared__ float red[4][EM];
  const int b = blockIdx.x >> 6;
  const int ch = blockIdx.x & 63;
  const int g = threadIdx.x >> 6;
  const int l = threadIdx.x & 63;
  const int s0 = ch * 64 + g * 16;
  const float* xb = X + (size_t)b * SLEN * EM;
  const float* wb = w + (size_t)b * SLEN;
  float4 acc = make_float4(0.f, 0.f, 0.f, 0.f);
#pragma unroll
  for (int i = 0; i < 16; ++i) {
    int s = s0 + i;
    float ws_ = wb[s];
    float4 v = *(const float4*)(xb + (size_t)s * EM + l * 4);
    acc.x = fmaf(ws_, v.x, acc.x);
    acc.y = fmaf(ws_, v.y, acc.y);
    acc.z = fmaf(ws_, v.z, acc.z);
    acc.w = fmaf(ws_, v.w, acc.w);
  }
  *(float4*)(&red[g][l * 4]) = acc;
  __syncthreads();
  if (g == 0) {
    float4 r0 = *(const float4*)(&red[0][l * 4]);
    float4 r1 = *(const float4*)(&red[1][l * 4]);
    float4 r2 = *(const float4*)(&red[2][l * 4]);
    float4 r3 = *(const float4*)(&red[3][l * 4]);
    float4 o;
    o.x = (r0.x + r1.x) + (r2.x + r3.x);
    o.y = (r0.y + r1.y) + (r2.y + r3.y);
    o.z = (r0.z + r1.z) + (r2.z + r3.z);
    o.w = (r0.w + r1.w) + (r2.w + r3.w);
    *(float4*)(part + (size_t)blockIdx.x * EM + l * 4) = o;
  }
}

// ---- K4: reduce 64 partials per (b,e) -> out ----
__global__ __launch_bounds__(256) void k4_reduce(const float* __restrict__ part,
                                                 float* __restrict__ out) {
  const int b = blockIdx.x;
  const int e = threadIdx.x;
  float s = 0.f;
#pragma unroll 8
  for (int k = 0; k < 64; ++k) s += part[((size_t)b * 64 + k) * EM + e];
  out[(size_t)b * EM + e] = s;
}

extern "C" void kernel_launch(void* const* d_in, const int* in_sizes, int n_in,
                              void* d_out, int out_size, void* d_ws, size_t ws_size,
                              hipStream_t stream) {
  const float* X = (const float*)d_in[0];
  const unsigned char* mask = (const unsigned char*)d_in[1];
  const float* w_query = (const float*)d_in[2];
  const float* wq = (const float*)d_in[3];
  const float* bq = (const float*)d_in[4];
  const float* wk = (const float*)d_in[5];
  const float* bk = (const float*)d_in[6];
  const float* we = (const float*)d_in[7];
  const float* be = (const float*)d_in[8];
  float* out = (float*)d_out;
  float* ws = (float*)d_ws;

  unsigned short* wkb2 = (unsigned short*)(ws + WS_WKB);
  float* energy = ws + WS_EN;
  float* cscalar = ws + WS_CONST;
  float* weights = ws + WS_W;
  float* part = ws + WS_PART;

  k0_cvt<<<32, 256, 0, stream>>>(wk, wkb2);
  k0b_qscalar<<<1, 256, 0, stream>>>(w_query, wq, bq, we, be, cscalar);
  k1_energy<<<NROWS / 256, 512, 0, stream>>>(X, wkb2, bk, we, energy);
  k2_softmax<<<BS, 256, 0, stream>>>(energy, mask, cscalar, weights);
  k3_wsum<<<BS * 64, 256, 0, stream>>>(X, weights, part);
  k4_reduce<<<BS, 256, 0, stream>>>(part, out);
}

// Round 11
// 280.542 us; speedup vs baseline: 1.0258x; 1.0258x over previous
//
#include <hip/hip_runtime.h>

#define BS   32
#define SLEN 4096
#define EM   256
#define NROWS (BS * SLEN)  // 131072

typedef __attribute__((ext_vector_type(8))) short bf16x8;
typedef __attribute__((ext_vector_type(4))) float f32x4;

// ---------------- ws layout (floats) ----------------
#define WS_WKB   0         // 32768  : wk bf16, fragment-major [kq][e][8]
#define WS_EN    32768     // 262144 : partial energy, 2 col-halves
#define WS_CONST 294912    // 16     : scalar energy_q + be
#define WS_W     294928    // 131072 : softmax weights
#define WS_PART  426000    // 524288 : wsum partials (2048 blocks) x 256

__device__ inline short f2bf(float x) {
  union { float f; unsigned u; } v; v.f = x;
  unsigned r = v.u + 0x7fffu + ((v.u >> 16) & 1u);  // RNE
  return (short)(r >> 16);
}

// packed f32x2 -> bf16x2 (RNE), gfx950 v_cvt_pk_bf16_f32 (no builtin; T12 recipe)
__device__ inline unsigned cvtpk(float lo, float hi) {
  unsigned r;
  asm("v_cvt_pk_bf16_f32 %0, %1, %2" : "=v"(r) : "v"(lo), "v"(hi));
  return r;
}
__device__ inline bf16x8 cvt8(float4 a, float4 b) {
  union { bf16x8 v; unsigned u[4]; } r;
  r.u[0] = cvtpk(a.x, a.y);
  r.u[1] = cvtpk(a.z, a.w);
  r.u[2] = cvtpk(b.x, b.y);
  r.u[3] = cvtpk(b.z, b.w);
  return r.v;
}

#define GLOAD_LDS16(g, l)                                                  \
  __builtin_amdgcn_global_load_lds(                                        \
      (const __attribute__((address_space(1))) unsigned int*)(g),          \
      (__attribute__((address_space(3))) unsigned int*)(l), 16, 0, 0)

// ---- K0: wk fp32 [e][k] -> bf16 fragment-major: 16B chunk index kq*256+e ----
__global__ __launch_bounds__(256) void k0_cvt(const float* __restrict__ wk,
                                              unsigned short* __restrict__ wkb2) {
  int gid = blockIdx.x * 256 + threadIdx.x;  // 8192
  int e = gid >> 5, kq = gid & 31;
  const float* src = wk + (size_t)e * EM + kq * 8;
  float4 v0 = *(const float4*)src;
  float4 v1 = *(const float4*)(src + 4);
  bf16x8 pk;
  pk[0] = f2bf(v0.x); pk[1] = f2bf(v0.y); pk[2] = f2bf(v0.z); pk[3] = f2bf(v0.w);
  pk[4] = f2bf(v1.x); pk[5] = f2bf(v1.y); pk[6] = f2bf(v1.z); pk[7] = f2bf(v1.w);
  *(bf16x8*)(wkb2 + ((size_t)kq * 256 + e) * 8) = pk;
}

// ---- K0b: scalar query path ----
__global__ __launch_bounds__(256) void k0b_qscalar(const float* __restrict__ w_query,
                                                   const float* __restrict__ wq,
                                                   const float* __restrict__ bq,
                                                   const float* __restrict__ we,
                                                   const float* __restrict__ be,
                                                   float* __restrict__ outc) {
  int t = threadIdx.x;  // t = e
  const float* row = wq + (size_t)t * EM;
  float4 a4 = make_float4(0.f, 0.f, 0.f, 0.f);
#pragma unroll 8
  for (int j = 0; j < 64; ++j) {
    float4 r = *(const float4*)(row + j * 4);
    float4 q = *(const float4*)(w_query + j * 4);
    a4.x = fmaf(r.x, q.x, a4.x);
    a4.y = fmaf(r.y, q.y, a4.y);
    a4.z = fmaf(r.z, q.z, a4.z);
    a4.w = fmaf(r.w, q.w, a4.w);
  }
  float a = (a4.x + a4.y) + (a4.z + a4.w) + bq[t];
  float kv = fmaxf(a, 0.f);
  float z = __expf(kv + kv);
  float v = we[t] * (1.f - __fdividef(2.f, z + 1.f));
#pragma unroll
  for (int off = 32; off >= 1; off >>= 1) v += __shfl_xor(v, off, 64);
  __shared__ float red[4];
  if ((t & 63) == 0) red[t >> 6] = v;
  __syncthreads();
  if (t == 0) outc[0] = red[0] + red[1] + red[2] + red[3] + be[0];
}

// ---- K1 (MFMA, col-split, half-B-in-LDS, ONE barrier) ----
// Grid 1024 = 512 row-blocks x 2 col-halves. 512 thr = 8 waves.
// Wave w owns rows blk*256 + w*32 + [0,32); block col-half ch covers
// e in [ch*128, ch*128+128). acc[2][8] = 64 f32/lane -> fits the 128-VGPR
// allocation observed for 512-thr blocks (R8/R10 spilled with acc=128).
// Bs = 64KB (half of fragment-major wkb2; contiguous per (kq,half)) ->
// 2 blocks/CU -> 4 waves/SIMD latency hiding. One barrier after staging;
// K-loop barrier-free: prefetch next A, cvt_pk, 8 ds_read_b128, 16 MFMA.
// Partial energies per half written to energy[ch*NROWS + row]; k2 sums.
__global__ __launch_bounds__(512) void k1_energy(const float* __restrict__ X,
                                                 const unsigned short* __restrict__ wkb2,
                                                 const float* __restrict__ bk,
                                                 const float* __restrict__ we,
                                                 float* __restrict__ energy) {
  __shared__ char Bs[65536];
  const int tid = threadIdx.x;
  const int l = tid & 63;
  const int w = tid >> 6;            // wave 0..7
  const int lr = l & 15, lk = l >> 4;
  const int ch = blockIdx.x & 1;
  const int blk = blockIdx.x >> 1;
  const int row0 = blk * 256 + w * 32;

  // ---- stage this col-half of B: 64 segs of 1KB; wave w does segs w*8.. ----
#pragma unroll
  for (int q = 0; q < 8; ++q) {
    int g = w * 8 + q;                 // 0..63
    int kq = g >> 1;                   // k-chunk pair index 0..31
    const char* src = (const char*)wkb2 + kq * 4096 + ch * 2048 + (g & 1) * 1024 + l * 16;
    GLOAD_LDS16(src, Bs + g * 1024);
  }

  f32x4 acc[2][8];
#pragma unroll
  for (int n = 0; n < 8; ++n) {
    float b = bk[ch * 128 + n * 16 + lr];  // dies after init
    acc[0][n] = (f32x4){b, b, b, b};
    acc[1][n] = acc[0][n];
  }

  // first A tile in flight before the barrier (independent of LDS)
  const float* xbase = X + (size_t)(row0 + lr) * EM + lk * 8;
  float4 c00 = *(const float4*)(xbase);
  float4 c01 = *(const float4*)(xbase + 4);
  float4 c10 = *(const float4*)(xbase + 16 * EM);
  float4 c11 = *(const float4*)(xbase + 16 * EM + 4);

  __syncthreads();  // only barrier: B resident from here on

#pragma unroll
  for (int s = 0; s < 8; ++s) {
    float4 n00, n01, n10, n11;
    if (s < 7) {
      const float* nx = xbase + (s + 1) * 32;
      n00 = *(const float4*)(nx);
      n01 = *(const float4*)(nx + 4);
      n10 = *(const float4*)(nx + 16 * EM);
      n11 = *(const float4*)(nx + 16 * EM + 4);
    }
    bf16x8 a0 = cvt8(c00, c01);
    bf16x8 a1 = cvt8(c10, c11);
    const char* bp = Bs + s * 8192 + lk * 2048 + lr * 16;
#pragma unroll
    for (int n = 0; n < 8; ++n) {
      bf16x8 bfr = *(const bf16x8*)(bp + n * 256);
      acc[0][n] = __builtin_amdgcn_mfma_f32_16x16x32_bf16(a0, bfr, acc[0][n], 0, 0, 0);
      acc[1][n] = __builtin_amdgcn_mfma_f32_16x16x32_bf16(a1, bfr, acc[1][n], 0, 0, 0);
    }
    c00 = n00; c01 = n01; c10 = n10; c11 = n11;
  }

  // ---- epilogue: partial p over this half: sumw - 2*sum(we*r), r=1/(e^2x+1)
  float sumw = 0.f, w2[8];
#pragma unroll
  for (int n = 0; n < 8; ++n) {
    float wv = we[EM + ch * 128 + n * 16 + lr];
    sumw += wv;
    w2[n] = -2.f * wv;
  }
  float* eout = energy + (size_t)ch * NROWS;
#pragma unroll
  for (int i = 0; i < 2; ++i) {
#pragma unroll
    for (int r = 0; r < 4; ++r) {
      float p = sumw;
#pragma unroll
      for (int n = 0; n < 8; ++n) {
        float kv = fmaxf(acc[i][n][r], 0.f);
        float z = __expf(kv + kv);
        p = fmaf(w2[n], __fdividef(1.f, z + 1.f), p);
      }
#pragma unroll
      for (int off = 1; off <= 8; off <<= 1) p += __shfl_xor(p, off, 16);
      if (lr == 0) eout[row0 + i * 16 + lk * 4 + r] = p;
    }
  }
}

// ---- K2: per-batch masked softmax; energy = half0 + half1 + C ----
__global__ __launch_bounds__(256) void k2_softmax(const float* __restrict__ energy,
                                                  const unsigned char* __restrict__ mask,
                                                  const float* __restrict__ cptr,
                                                  float* __restrict__ wout) {
  const int b = blockIdx.x;
  const int t = threadIdx.x;
  const float C = cptr[0];
  const bool mask_is_byte = (mask[1] | mask[2] | mask[3]) != 0;
  const int* mask32 = (const int*)mask;
  const float* eb0 = energy + (size_t)b * SLEN;
  const float* eb1 = energy + NROWS + (size_t)b * SLEN;
  float v[16];
  float m = -3.4e38f;
#pragma unroll
  for (int i = 0; i < 16; ++i) {
    int s = t + i * 256;
    int mv = mask_is_byte ? (int)mask[(size_t)b * SLEN + s]
                          : mask32[(size_t)b * SLEN + s];
    float x = mv ? (eb0[s] + eb1[s] + C) : 1.4012984643248171e-45f;
    v[i] = x;
    m = fmaxf(m, x);
  }
  __shared__ float red[8];
#pragma unroll
  for (int off = 32; off >= 1; off >>= 1) m = fmaxf(m, __shfl_xor(m, off, 64));
  if ((t & 63) == 0) red[t >> 6] = m;
  __syncthreads();
  m = fmaxf(fmaxf(red[0], red[1]), fmaxf(red[2], red[3]));
  float s_ = 0.f;
#pragma unroll
  for (int i = 0; i < 16; ++i) {
    v[i] = __expf(v[i] - m);
    s_ += v[i];
  }
#pragma unroll
  for (int off = 32; off >= 1; off >>= 1) s_ += __shfl_xor(s_, off, 64);
  if ((t & 63) == 0) red[4 + (t >> 6)] = s_;
  __syncthreads();
  float inv = 1.f / (red[4] + red[5] + red[6] + red[7]);
  float* wb = wout + (size_t)b * SLEN;
#pragma unroll
  for (int i = 0; i < 16; ++i) wb[t + i * 256] = v[i] * inv;
}

// ---- K3: partial weighted sums. 2048 blocks = 32b x 64ch(64 s each) ----
__global__ __launch_bounds__(256) void k3_wsum(const float* __restrict__ X,
                                               const float* __restrict__ w,
                                               float* __restrict__ part) {
  __shared__ float red[4][EM];
  const int b = blockIdx.x >> 6;
  const int ch = blockIdx.x & 63;
  const int g = threadIdx.x >> 6;
  const int l = threadIdx.x & 63;
  const int s0 = ch * 64 + g * 16;
  const float* xb = X + (size_t)b * SLEN * EM;
  const float* wb = w + (size_t)b * SLEN;
  float4 acc = make_float4(0.f, 0.f, 0.f, 0.f);
#pragma unroll
  for (int i = 0; i < 16; ++i) {
    int s = s0 + i;
    float ws_ = wb[s];
    float4 v = *(const float4*)(xb + (size_t)s * EM + l * 4);
    acc.x = fmaf(ws_, v.x, acc.x);
    acc.y = fmaf(ws_, v.y, acc.y);
    acc.z = fmaf(ws_, v.z, acc.z);
    acc.w = fmaf(ws_, v.w, acc.w);
  }
  *(float4*)(&red[g][l * 4]) = acc;
  __syncthreads();
  if (g == 0) {
    float4 r0 = *(const float4*)(&red[0][l * 4]);
    float4 r1 = *(const float4*)(&red[1][l * 4]);
    float4 r2 = *(const float4*)(&red[2][l * 4]);
    float4 r3 = *(const float4*)(&red[3][l * 4]);
    float4 o;
    o.x = (r0.x + r1.x) + (r2.x + r3.x);
    o.y = (r0.y + r1.y) + (r2.y + r3.y);
    o.z = (r0.z + r1.z) + (r2.z + r3.z);
    o.w = (r0.w + r1.w) + (r2.w + r3.w);
    *(float4*)(part + (size_t)blockIdx.x * EM + l * 4) = o;
  }
}

// ---- K4: reduce 64 partials per (b,e) -> out ----
__global__ __launch_bounds__(256) void k4_reduce(const float* __restrict__ part,
                                                 float* __restrict__ out) {
  const int b = blockIdx.x;
  const int e = threadIdx.x;
  float s = 0.f;
#pragma unroll 8
  for (int k = 0; k < 64; ++k) s += part[((size_t)b * 64 + k) * EM + e];
  out[(size_t)b * EM + e] = s;
}

extern "C" void kernel_launch(void* const* d_in, const int* in_sizes, int n_in,
                              void* d_out, int out_size, void* d_ws, size_t ws_size,
                              hipStream_t stream) {
  const float* X = (const float*)d_in[0];
  const unsigned char* mask = (const unsigned char*)d_in[1];
  const float* w_query = (const float*)d_in[2];
  const float* wq = (const float*)d_in[3];
  const float* bq = (const float*)d_in[4];
  const float* wk = (const float*)d_in[5];
  const float* bk = (const float*)d_in[6];
  const float* we = (const float*)d_in[7];
  const float* be = (const float*)d_in[8];
  float* out = (float*)d_out;
  float* ws = (float*)d_ws;

  unsigned short* wkb2 = (unsigned short*)(ws + WS_WKB);
  float* energy = ws + WS_EN;        // 2 x NROWS partials
  float* cscalar = ws + WS_CONST;
  float* weights = ws + WS_W;
  float* part = ws + WS_PART;

  k0_cvt<<<32, 256, 0, stream>>>(wk, wkb2);
  k0b_qscalar<<<1, 256, 0, stream>>>(w_query, wq, bq, we, be, cscalar);
  k1_energy<<<1024, 512, 0, stream>>>(X, wkb2, bk, we, energy);
  k2_softmax<<<BS, 256, 0, stream>>>(energy, mask, cscalar, weights);
  k3_wsum<<<BS * 64, 256, 0, stream>>>(X, weights, part);
  k4_reduce<<<BS, 256, 0, stream>>>(part, out);
}